// Round 4
// baseline (254.866 us; speedup 1.0000x reference)
//
#include <hip/hip_runtime.h>

// Problem constants
#define Bn  16
#define Ln  224
#define K1n 8192
#define Pn  16
#define NCHUNK 32   // k-chunks per batch (256 k each)

// ws layout (floats):
//   ws_sum : [Bn][NCHUNK][Pn]   per-block partial sums
//   ws_max : [Bn][NCHUNK][Pn]   per-block partial maxes
//   ws_mid : [Bn][Pn]           h3 at k = K1/2
// Every slot unconditionally written by exactly one block -> no zeroing,
// no atomics, safe under the harness's 0xAA ws poison.

// ---------------------------------------------------------------------------
// Kernel 1: one wave per block; each lane handles 4 consecutive k (float4).
// Block covers 256 k. Grid: 512 blocks (32 per b), 64 threads.
// LDS broadcast of w3c amortized over 256 elements/wave-instruction.
// ---------------------------------------------------------------------------
__global__ __launch_bounds__(64) void k_stats(
    const float* __restrict__ y,      // [B, L, K1] f32
    const float* __restrict__ w3c,    // [1, L, P]  f32
    const float* __restrict__ sigma,  // [1]        f32
    float* __restrict__ ws_sum,
    float* __restrict__ ws_max,
    float* __restrict__ ws_mid)
{
    __shared__ float s_w3c[Ln][Pn];   // 14 KiB
    __shared__ float s_csq[Pn];

    const int tid   = threadIdx.x;            // 0..63
    const int b     = blockIdx.x >> 5;
    const int chunk = blockIdx.x & 31;
    const int kb    = chunk << 8;             // 256 k per block

    for (int i = tid; i < Ln * Pn; i += 64) s_w3c[i >> 4][i & 15] = w3c[i];
    __syncthreads();
    if (tid < Pn) {
        float cs = 0.f;
        for (int l = 0; l < Ln; ++l) { float v = s_w3c[l][tid]; cs = fmaf(v, v, cs); }
        s_csq[tid] = cs;
    }
    __syncthreads();

    float cross0[Pn], cross1[Pn], cross2[Pn], cross3[Pn];
#pragma unroll
    for (int p = 0; p < Pn; ++p) { cross0[p] = cross1[p] = cross2[p] = cross3[p] = 0.f; }
    float ysq0 = 0.f, ysq1 = 0.f, ysq2 = 0.f, ysq3 = 0.f;

    const float4* yp = reinterpret_cast<const float4*>(
                           y + (size_t)b * Ln * K1n + kb) + tid;
#pragma unroll 8
    for (int l = 0; l < Ln; ++l) {
        float4 v = yp[l * (K1n / 4)];
        ysq0 = fmaf(v.x, v.x, ysq0);
        ysq1 = fmaf(v.y, v.y, ysq1);
        ysq2 = fmaf(v.z, v.z, ysq2);
        ysq3 = fmaf(v.w, v.w, ysq3);
#pragma unroll
        for (int p = 0; p < Pn; ++p) {
            float w = s_w3c[l][p];
            cross0[p] = fmaf(v.x, w, cross0[p]);
            cross1[p] = fmaf(v.y, w, cross1[p]);
            cross2[p] = fmaf(v.z, w, cross2[p]);
            cross3[p] = fmaf(v.w, w, cross3[p]);
        }
    }

    const float sg = sigma[0];
    const float nh = -0.5f / (sg * sg);
    const bool midw = (kb == (K1n / 2)) && (tid == 0);   // k=4096 -> lane0, j=0

#pragma unroll
    for (int p = 0; p < Pn; ++p) {
        float c = s_csq[p];
        float d0 = fmaxf(ysq0 + c - 2.f * cross0[p], 0.f);
        float d1 = fmaxf(ysq1 + c - 2.f * cross1[p], 0.f);
        float d2_ = fmaxf(ysq2 + c - 2.f * cross2[p], 0.f);
        float d3 = fmaxf(ysq3 + c - 2.f * cross3[p], 0.f);
        float h0 = __expf(d0 * nh);
        float h1 = __expf(d1 * nh);
        float h2 = __expf(d2_ * nh);
        float h3 = __expf(d3 * nh);
        if (midw) ws_mid[b * Pn + p] = h0;

        float s = (h0 + h1) + (h2 + h3);
        float m = fmaxf(fmaxf(h0, h1), fmaxf(h2, h3));
#pragma unroll
        for (int off = 32; off > 0; off >>= 1) {
            s += __shfl_down(s, off, 64);
            m = fmaxf(m, __shfl_down(m, off, 64));
        }
        if (tid == 0) {
            const int base = (b * NCHUNK + chunk) * Pn + p;
            ws_sum[base] = s;
            ws_max[base] = m;
        }
    }
}

// ---------------------------------------------------------------------------
// Kernel 2: reduce partials + tiny finalize + out = h4 + w3_w@(a-d2), float4.
// Grid: 512 blocks (32 per b), 64 threads, 4 k per lane.
// ---------------------------------------------------------------------------
__global__ __launch_bounds__(64) void k_out(
    const float* __restrict__ a,      // [B, P, K1] f32
    const float* __restrict__ d2,     // [B, P, K1] f32
    const float* __restrict__ w3w,    // [P, P] f32
    const float* __restrict__ b3w,    // [P, P] f32
    const float* __restrict__ caw,    // [2, P] f32
    const float* __restrict__ ws_sum,
    const float* __restrict__ ws_max,
    const float* __restrict__ ws_mid,
    float* __restrict__ out)          // [B, P, K1] f32
{
    __shared__ float s_w3w[Pn][Pn];
    __shared__ float s_avg[Pn], s_mx[Pn], s_mid[Pn], s_comb[Pn], s_h4[Pn];
    __shared__ float s_t[2];

    const int tid = threadIdx.x;      // 0..63
    const int b   = blockIdx.x >> 5;
    const int kb  = (blockIdx.x & 31) << 8;

    for (int i = tid; i < Pn * Pn; i += 64) s_w3w[i >> 4][i & 15] = w3w[i];

    if (tid < Pn) {
        float s = 0.f, m = -1.f;
        for (int g = 0; g < NCHUNK; ++g) {
            const int idx = (b * NCHUNK + g) * Pn + tid;
            s += ws_sum[idx];
            m = fmaxf(m, ws_max[idx]);
        }
        s_avg[tid] = s * (1.f / (float)K1n);
        s_mx[tid]  = m;
        s_mid[tid] = ws_mid[b * Pn + tid];
    }
    __syncthreads();

    if (tid < 2) {
        float t1 = 0.f, t2 = 0.f;
        for (int p = 0; p < Pn; ++p) {
            float cw = caw[tid * Pn + p];
            t1 = fmaf(cw, s_avg[p], t1);
            t2 = fmaf(cw, s_mx[p],  t2);
        }
        t1 = (t1 > 0.f) ? t1 : 0.01f * t1;   // leaky_relu
        t2 = (t2 > 0.f) ? t2 : 0.01f * t2;
        s_t[tid] = t1 + t2;
    }
    __syncthreads();

    if (tid < Pn) {
        float t0 = s_t[0], u1 = s_t[1];
        float mt = fmaxf(t0, u1);
        float e0 = __expf(t0 - mt), e1 = __expf(u1 - mt);
        float inv = 1.f / (e0 + e1);
        s_comb[tid] = (e0 * inv) * s_mid[tid] + (e1 * inv) * s_avg[tid];
    }
    __syncthreads();

    if (tid < Pn) {
        float h = 0.f;
        for (int q = 0; q < Pn; ++q) h = fmaf(b3w[tid * Pn + q], s_comb[q], h);
        s_h4[tid] = h;
    }
    __syncthreads();

    // diff[q] = (a - d2)[b, q, k0..k0+3]; out[b,p,k] = h4[p] + w3_w[p,:]·diff
    const size_t base = (size_t)b * Pn * K1n + kb + 4 * tid;
    float4 diff[Pn];
#pragma unroll
    for (int q = 0; q < Pn; ++q) {
        float4 av = *reinterpret_cast<const float4*>(a  + base + (size_t)q * K1n);
        float4 dv = *reinterpret_cast<const float4*>(d2 + base + (size_t)q * K1n);
        diff[q].x = av.x - dv.x;
        diff[q].y = av.y - dv.y;
        diff[q].z = av.z - dv.z;
        diff[q].w = av.w - dv.w;
    }
#pragma unroll
    for (int p = 0; p < Pn; ++p) {
        float4 h2;
        h2.x = h2.y = h2.z = h2.w = s_h4[p];
#pragma unroll
        for (int q = 0; q < Pn; ++q) {
            const float w = s_w3w[p][q];
            h2.x = fmaf(w, diff[q].x, h2.x);
            h2.y = fmaf(w, diff[q].y, h2.y);
            h2.z = fmaf(w, diff[q].z, h2.z);
            h2.w = fmaf(w, diff[q].w, h2.w);
        }
        *reinterpret_cast<float4*>(out + base + (size_t)p * K1n) = h2;
    }
}

// ---------------------------------------------------------------------------
extern "C" void kernel_launch(void* const* d_in, const int* in_sizes, int n_in,
                              void* d_out, int out_size, void* d_ws, size_t ws_size,
                              hipStream_t stream) {
    const float* a     = (const float*)d_in[0];
    const float* d2    = (const float*)d_in[1];
    const float* y     = (const float*)d_in[2];
    const float* w3w   = (const float*)d_in[3];
    const float* b3w   = (const float*)d_in[4];
    const float* w3c   = (const float*)d_in[5];
    const float* sigma = (const float*)d_in[6];
    const float* caw   = (const float*)d_in[7];

    float* ws_sum = (float*)d_ws;
    float* ws_max = ws_sum + Bn * NCHUNK * Pn;
    float* ws_mid = ws_max + Bn * NCHUNK * Pn;

    k_stats<<<dim3(Bn * NCHUNK), dim3(64), 0, stream>>>(
        y, w3c, sigma, ws_sum, ws_max, ws_mid);

    k_out<<<dim3(Bn * NCHUNK), dim3(64), 0, stream>>>(
        a, d2, w3w, b3w, caw, ws_sum, ws_max, ws_mid, (float*)d_out);
}

// Round 5
// 214.142 us; speedup vs baseline: 1.1902x; 1.1902x over previous
//
#include <hip/hip_runtime.h>

// Problem constants
#define Bn  16
#define Ln  224
#define K1n 8192
#define Pn  16
#define NCHUNK 32   // k-chunks per batch (256 k each)

// ws layout (floats):
//   ws_sum : [Bn][NCHUNK][Pn]   per-block partial sums
//   ws_max : [Bn][NCHUNK][Pn]   per-block partial maxes
//   ws_mid : [Bn][Pn]           h3 at k = K1/2
// Every slot unconditionally written by exactly one block -> no zeroing,
// no atomics, safe under the harness's 0xAA ws poison.

// ---------------------------------------------------------------------------
// Kernel 1: per-(b,k) compute h3[p]; per-block reduce sum/max over its 256 k.
// Grid: 512 blocks (32 per b), 256 threads, one k per thread (scalar loads
// for max TLP: 8 waves/CU). w3c row values are wave-uniform -> read from
// global so the compiler can use scalar loads (K$) instead of LDS broadcast.
// ---------------------------------------------------------------------------
__global__ __launch_bounds__(256) void k_stats(
    const float* __restrict__ y,      // [B, L, K1] f32
    const float* __restrict__ w3c,    // [1, L, P]  f32
    const float* __restrict__ sigma,  // [1]        f32
    float* __restrict__ ws_sum,
    float* __restrict__ ws_max,
    float* __restrict__ ws_mid)
{
    __shared__ float s_csq_part[16][Pn];
    __shared__ float s_csq[Pn];
    __shared__ float s_part_s[4][Pn];
    __shared__ float s_part_m[4][Pn];

    const int tid   = threadIdx.x;
    const int b     = blockIdx.x >> 5;         // 32 blocks per batch
    const int chunk = blockIdx.x & 31;
    const int k     = (chunk << 8) + tid;

    // c_sq[p] = sum_l w3c[l][p]^2 — cooperative: 16 subs x 16 p
    {
        const int p   = tid & 15;
        const int sub = tid >> 4;              // 0..15
        float cs = 0.f;
#pragma unroll
        for (int l = sub; l < Ln; l += 16) {
            float v = w3c[l * Pn + p];
            cs = fmaf(v, v, cs);
        }
        s_csq_part[sub][p] = cs;
    }
    __syncthreads();
    if (tid < Pn) {
        float cs = 0.f;
#pragma unroll
        for (int s = 0; s < 16; ++s) cs += s_csq_part[s][tid];
        s_csq[tid] = cs;
    }
    __syncthreads();

    // Main loop over L: y_sq and cross[p]. w3c row via wave-uniform (scalar)
    // loads; y via coalesced per-lane scalar loads, deep unroll for MLP.
    float cross[Pn];
#pragma unroll
    for (int p = 0; p < Pn; ++p) cross[p] = 0.f;
    float ysq = 0.f;

    const float* yp = y + (size_t)b * Ln * K1n + k;
#pragma unroll 16
    for (int l = 0; l < Ln; ++l) {
        float v = yp[(size_t)l * K1n];
        ysq = fmaf(v, v, ysq);
        const float* wrow = w3c + l * Pn;      // uniform address -> s_load
#pragma unroll
        for (int p = 0; p < Pn; ++p) cross[p] = fmaf(v, wrow[p], cross[p]);
    }

    const float sg = sigma[0];
    const float nh = -0.5f / (sg * sg);

    float h3[Pn];
#pragma unroll
    for (int p = 0; p < Pn; ++p) {
        float d = fmaxf(ysq + s_csq[p] - 2.f * cross[p], 0.f);
        h3[p] = __expf(d * nh);
    }

    // mid = h3[b, p, K1/2] : k == 4096 -> chunk == 16, tid == 0
    if (k == (K1n / 2)) {
#pragma unroll
        for (int p = 0; p < Pn; ++p) ws_mid[b * Pn + p] = h3[p];
    }

    // Wave-level reduce (sum & max) per p, then cross-wave via LDS
    const int lane = tid & 63;
    const int wv   = tid >> 6;
#pragma unroll
    for (int p = 0; p < Pn; ++p) {
        float s = h3[p];
        float m = h3[p];
#pragma unroll
        for (int off = 32; off > 0; off >>= 1) {
            s += __shfl_down(s, off, 64);
            m = fmaxf(m, __shfl_down(m, off, 64));
        }
        if (lane == 0) { s_part_s[wv][p] = s; s_part_m[wv][p] = m; }
    }
    __syncthreads();
    if (tid < Pn) {
        float s = s_part_s[0][tid] + s_part_s[1][tid] + s_part_s[2][tid] + s_part_s[3][tid];
        float m = fmaxf(fmaxf(s_part_m[0][tid], s_part_m[1][tid]),
                        fmaxf(s_part_m[2][tid], s_part_m[3][tid]));
        const int base = (b * NCHUNK + chunk) * Pn + tid;
        ws_sum[base] = s;
        ws_max[base] = m;
    }
}

// ---------------------------------------------------------------------------
// Kernel 2: reduce partials + tiny finalize (h4[b,p]) + out = h4 + w3_w@(a-d2).
// Grid: 512 blocks (32 per b), 256 threads, one k per thread. (R3 structure —
// it was not the bottleneck.)
// ---------------------------------------------------------------------------
__global__ __launch_bounds__(256) void k_out(
    const float* __restrict__ a,      // [B, P, K1] f32
    const float* __restrict__ d2,     // [B, P, K1] f32
    const float* __restrict__ w3w,    // [P, P] f32
    const float* __restrict__ b3w,    // [P, P] f32
    const float* __restrict__ caw,    // [2, P] f32
    const float* __restrict__ ws_sum,
    const float* __restrict__ ws_max,
    const float* __restrict__ ws_mid,
    float* __restrict__ out)          // [B, P, K1] f32
{
    __shared__ float s_w3w[Pn][Pn];
    __shared__ float s_red_s[16][Pn];   // 16 groups x 16 p
    __shared__ float s_red_m[16][Pn];
    __shared__ float s_avg[Pn], s_mx[Pn], s_mid[Pn], s_comb[Pn], s_h4[Pn];
    __shared__ float s_t[2];

    const int tid = threadIdx.x;
    const int b   = blockIdx.x >> 5;
    const int k   = ((blockIdx.x & 31) << 8) + tid;

    if (tid < Pn * Pn) s_w3w[tid >> 4][tid & 15] = w3w[tid];

    // Parallel partial-reduce: thread (grp, p) handles chunks grp and grp+16
    {
        const int p   = tid & 15;
        const int grp = tid >> 4;          // 0..15
        const int i0  = (b * NCHUNK + grp)      * Pn + p;
        const int i1  = (b * NCHUNK + grp + 16) * Pn + p;
        if (grp < 16) {
            s_red_s[grp][p] = ws_sum[i0] + ws_sum[i1];
            s_red_m[grp][p] = fmaxf(ws_max[i0], ws_max[i1]);
        }
    }
    __syncthreads();
    if (tid < Pn) {
        float s = 0.f, m = -1.f;
        for (int g = 0; g < 16; ++g) {
            s += s_red_s[g][tid];
            m = fmaxf(m, s_red_m[g][tid]);
        }
        s_avg[tid] = s * (1.f / (float)K1n);
        s_mx[tid]  = m;
        s_mid[tid] = ws_mid[b * Pn + tid];
    }
    __syncthreads();

    if (tid < 2) {
        float t1 = 0.f, t2 = 0.f;
        for (int p = 0; p < Pn; ++p) {
            float cw = caw[tid * Pn + p];
            t1 = fmaf(cw, s_avg[p], t1);
            t2 = fmaf(cw, s_mx[p],  t2);
        }
        t1 = (t1 > 0.f) ? t1 : 0.01f * t1;   // leaky_relu
        t2 = (t2 > 0.f) ? t2 : 0.01f * t2;
        s_t[tid] = t1 + t2;
    }
    __syncthreads();

    if (tid < Pn) {
        float t0 = s_t[0], u1 = s_t[1];
        float mt = fmaxf(t0, u1);
        float e0 = __expf(t0 - mt), e1 = __expf(u1 - mt);
        float inv = 1.f / (e0 + e1);
        s_comb[tid] = (e0 * inv) * s_mid[tid] + (e1 * inv) * s_avg[tid];
    }
    __syncthreads();

    if (tid < Pn) {
        float h = 0.f;
        for (int q = 0; q < Pn; ++q) h = fmaf(b3w[tid * Pn + q], s_comb[q], h);
        s_h4[tid] = h;
    }
    __syncthreads();

    // Main: diff[q] = (a - d2)[b, q, k]; out[b, p, k] = h4[p] + w3_w[p,:]·diff
    const size_t base = (size_t)b * Pn * K1n + (size_t)k;
    float diff[Pn];
#pragma unroll
    for (int q = 0; q < Pn; ++q) {
        float av = a [base + (size_t)q * K1n];
        float dv = d2[base + (size_t)q * K1n];
        diff[q] = av - dv;
    }
#pragma unroll
    for (int p = 0; p < Pn; ++p) {
        float h2 = 0.f;
#pragma unroll
        for (int q = 0; q < Pn; ++q) h2 = fmaf(s_w3w[p][q], diff[q], h2);
        out[base + (size_t)p * K1n] = h2 + s_h4[p];
    }
}

// ---------------------------------------------------------------------------
extern "C" void kernel_launch(void* const* d_in, const int* in_sizes, int n_in,
                              void* d_out, int out_size, void* d_ws, size_t ws_size,
                              hipStream_t stream) {
    const float* a     = (const float*)d_in[0];
    const float* d2    = (const float*)d_in[1];
    const float* y     = (const float*)d_in[2];
    const float* w3w   = (const float*)d_in[3];
    const float* b3w   = (const float*)d_in[4];
    const float* w3c   = (const float*)d_in[5];
    const float* sigma = (const float*)d_in[6];
    const float* caw   = (const float*)d_in[7];

    float* ws_sum = (float*)d_ws;
    float* ws_max = ws_sum + Bn * NCHUNK * Pn;
    float* ws_mid = ws_max + Bn * NCHUNK * Pn;

    k_stats<<<dim3(Bn * NCHUNK), dim3(256), 0, stream>>>(
        y, w3c, sigma, ws_sum, ws_max, ws_mid);

    k_out<<<dim3(Bn * NCHUNK), dim3(256), 0, stream>>>(
        a, d2, w3w, b3w, caw, ws_sum, ws_max, ws_mid, (float*)d_out);
}